// Round 4
// baseline (224.540 us; speedup 1.0000x reference)
//
#include <hip/hip_runtime.h>
#include <cstddef>

#define N_TOT   8
#define R_TOT   2048
#define NR_TOT  (N_TOT*R_TOT)      // 16384 points
#define KK      16
#define CL      64
#define CM      128
#define EPSV    1e-5f
#define CNTF    262144.0f

typedef float  f32x4  __attribute__((ext_vector_type(4)));
typedef short  bf16x8 __attribute__((ext_vector_type(8)));

union FragU { bf16x8 f; unsigned u[4]; };

__device__ __forceinline__ float elu_f(float x){
    return x > 0.f ? x : (__expf(x) - 1.f);
}

#if defined(__has_builtin) && __has_builtin(__builtin_amdgcn_cvt_pk_bf16_f32)
// gfx950 HW pack: 1 VALU op, RNE (follows default round mode)
__device__ __forceinline__ unsigned pk_bf16(float a, float b){
    auto v = __builtin_amdgcn_cvt_pk_bf16_f32(a, b);   // lo=a, hi=b
    unsigned u; __builtin_memcpy(&u, &v, 4);
    return u;
}
#else
__device__ __forceinline__ unsigned pk_bf16(float a, float b){   // RNE pack 2xbf16
    unsigned ua = __float_as_uint(a), ub = __float_as_uint(b);
    ua += 0x7fff + ((ua >> 16) & 1);
    ub += 0x7fff + ((ub >> 16) & 1);
    return (ua >> 16) | (ub & 0xffff0000u);
}
#endif
__device__ __forceinline__ float bf_lo(unsigned u){ return __uint_as_float(u << 16); }
__device__ __forceinline__ float bf_hi(unsigned u){ return __uint_as_float(u & 0xffff0000u); }

// split 4 floats -> (hi01, hi23, lo01, lo23); hi+lo == x to ~2^-17 rel
__device__ __forceinline__ void split4(const float* x, unsigned* o){
    unsigned h01 = pk_bf16(x[0], x[1]);
    unsigned h23 = pk_bf16(x[2], x[3]);
    float l0 = x[0] - bf_lo(h01), l1 = x[1] - bf_hi(h01);
    float l2 = x[2] - bf_lo(h23), l3 = x[3] - bf_hi(h23);
    o[0] = h01; o[1] = h23; o[2] = pk_bf16(l0, l1); o[3] = pk_bf16(l2, l3);
}

// ---------------- Pass 1: global BN stats (sum, sumsq per d) ----------------
__global__ __launch_bounds__(256) void xconv_stats(
    const float* __restrict__ p, const float* __restrict__ P, float* __restrict__ ws)
{
    float s1[3] = {0.f,0.f,0.f}, s2[3] = {0.f,0.f,0.f};
    const int total = NR_TOT * KK;
    for (int idx = blockIdx.x*256 + threadIdx.x; idx < total; idx += gridDim.x*256){
        int nr = idx >> 4;
        #pragma unroll
        for (int d = 0; d < 3; d++){
            float v = P[idx*3 + d] - p[nr*3 + d];
            s1[d] += v;
            s2[d] += v*v;
        }
    }
    #pragma unroll
    for (int off = 32; off > 0; off >>= 1){
        #pragma unroll
        for (int d = 0; d < 3; d++){
            s1[d] += __shfl_down(s1[d], off, 64);
            s2[d] += __shfl_down(s2[d], off, 64);
        }
    }
    __shared__ float red[4][6];
    int wave = threadIdx.x >> 6, lane = threadIdx.x & 63;
    if (lane == 0){
        #pragma unroll
        for (int d = 0; d < 3; d++){ red[wave][d] = s1[d]; red[wave][3+d] = s2[d]; }
    }
    __syncthreads();
    if (threadIdx.x < 6){
        float a = red[0][threadIdx.x] + red[1][threadIdx.x]
                + red[2][threadIdx.x] + red[3][threadIdx.x];
        atomicAdd(&ws[threadIdx.x], a);
    }
}

// ---------------- Pass 2: fused MFMA kernel ----------------
// 1024 blocks x 256 thr; each wave handles 4 points; full single-shot residency
// (4096 waves = 4 waves/SIMD exactly).
__global__ __launch_bounds__(256, 4) void xconv_main(
    const float* __restrict__ p,   const float* __restrict__ P,
    const float* __restrict__ F,
    const float* __restrict__ gamma,const float* __restrict__ beta,
    const float* __restrict__ w1,  const float* __restrict__ b1,
    const float* __restrict__ w2,  const float* __restrict__ b2,
    const float* __restrict__ midw,const float* __restrict__ midb,
    const float* __restrict__ mlpw,const float* __restrict__ mlpb,
    const float* __restrict__ endw,const float* __restrict__ endb,
    const float* __restrict__ ws,  float* __restrict__ out)
{
    __shared__ float sEndw[128*20];            // row stride 20 floats (80 B)

    const int tid  = threadIdx.x;
    const int lane = tid & 63;
    const int lo16 = lane & 15;
    const int quad = lane >> 4;
    const int wave = tid >> 6;

    // ---- stage endw [c][k] into LDS (rows padded to 80 B) ----
    {
        const float4* ep = (const float4*)endw;          // 512 float4
        float4 v0 = ep[tid*2], v1 = ep[tid*2 + 1];
        int c = tid >> 1, k0 = (tid & 1) * 8;
        float* dst = &sEndw[c*20 + k0];
        *(float4*)dst = v0; *(float4*)(dst + 4) = v1;
    }
    __syncthreads();

    // ---- BN scale/shift (finalize fused; uniform per wave) ----
    float sc[3], sh[3];
    #pragma unroll
    for (int d = 0; d < 3; d++){
        float mean = ws[d] / CNTF;
        float var  = ws[3+d] / CNTF - mean*mean;
        float s    = gamma[d] * rsqrtf(var + EPSV);
        sc[d] = s; sh[d] = beta[d] - mean*s;
    }

    // ---- static weight registers ----
    // w1/b1 packed bf16: q = s*32 + quad*8 + j
    unsigned w1pk[2][8][2];
    #pragma unroll
    for (int s = 0; s < 2; s++)
        #pragma unroll
        for (int j = 0; j < 8; j++){
            int q = s*32 + quad*8 + j;
            w1pk[s][j][0] = pk_bf16(w1[q],        w1[64 + q]);
            w1pk[s][j][1] = pk_bf16(w1[128 + q],  b1[q]);
        }
    // w2 B-frags: tile b (cols b*16+lo16), K-step s, rows quad*8+jj
    FragU w2f[4][2];
    #pragma unroll
    for (int b = 0; b < 4; b++)
        #pragma unroll
        for (int s = 0; s < 2; s++)
            #pragma unroll
            for (int d = 0; d < 4; d++){
                int q0 = s*32 + quad*8 + d*2;
                int idx = q0*64 + b*16 + lo16;
                w2f[b][s].u[d] = pk_bf16(w2[idx], w2[idx + 64]);
            }
    // mlp A-frags (mlpw^T, hi/lo split, quad-dup)
    FragU mlpA[2];
    {
        float mw[4];
        #pragma unroll
        for (int r = 0; r < 4; r++) mw[r] = mlpw[(quad*4 + r)*16 + lo16];
        unsigned o[4]; split4(mw, o);
        mlpA[0].u[0]=o[0]; mlpA[0].u[1]=o[1]; mlpA[0].u[2]=o[0]; mlpA[0].u[3]=o[1];
        mlpA[1].u[0]=o[2]; mlpA[1].u[1]=o[3]; mlpA[1].u[2]=o[2]; mlpA[1].u[3]=o[3];
    }
    float mlpbr[4];
    #pragma unroll
    for (int r = 0; r < 4; r++) mlpbr[r] = mlpb[quad*4 + r];
    // midw/midb for X0 cols quad*4+j
    float mw0[4], mw1[4], mw2[4], mbv[4];
    #pragma unroll
    for (int j = 0; j < 4; j++){
        int m2 = quad*4 + j;
        mw0[j] = midw[m2]; mw1[j] = midw[16 + m2]; mw2[j] = midw[32 + m2];
        mbv[j] = midb[m2];
    }
    float b2r[4];
    #pragma unroll
    for (int b = 0; b < 4; b++) b2r[b] = b2[b*16 + lo16];
    const float endb0 = endb[lane], endb1 = endb[64 + lane];

    const int wglobal = blockIdx.x*4 + wave;   // 0..4095

    #pragma unroll 1
    for (int it = 0; it < 4; it++){
        const int nr = wglobal*4 + it;

        // ---- issue all global loads up front (latency hidden by h1 VALU) ----
        const int pb = nr*48 + lo16*3;
        float P0 = P[pb], P1 = P[pb+1], P2 = P[pb+2];
        float pp0 = p[nr*3], pp1 = p[nr*3+1], pp2 = p[nr*3+2];
        float fv[4][4];                        // F[nr][quad*4+r][bt*16+lo16]
        #pragma unroll
        for (int bt = 0; bt < 4; bt++)
            #pragma unroll
            for (int r = 0; r < 4; r++)
                fv[bt][r] = F[(size_t)nr*1024 + (quad*4 + r)*64 + bt*16 + lo16];

        const float pn0 = (P0 - pp0)*sc[0] + sh[0];
        const float pn1 = (P1 - pp1)*sc[1] + sh[1];
        const float pn2 = (P2 - pp2)*sc[2] + sh[2];

        // ---- h1 A-frags (lift1 + ELU + bf16 pack), fully in-lane ----
        FragU hf[2];
        #pragma unroll
        for (int s = 0; s < 2; s++)
            #pragma unroll
            for (int d = 0; d < 4; d++){
                float e[2];
                #pragma unroll
                for (int h2 = 0; h2 < 2; h2++){
                    unsigned pa = w1pk[s][2*d + h2][0], pbk = w1pk[s][2*d + h2][1];
                    float h = bf_hi(pbk);
                    h = fmaf(pn0, bf_lo(pa), h);
                    h = fmaf(pn1, bf_hi(pa), h);
                    h = fmaf(pn2, bf_lo(pbk), h);
                    e[h2] = elu_f(h);
                }
                hf[s].u[d] = pk_bf16(e[0], e[1]);
            }

        // ---- X0 (exact fp32) -> split B-frag ----
        float x0[4];
        #pragma unroll
        for (int j = 0; j < 4; j++)
            x0[j] = fmaf(pn2, mw2[j], fmaf(pn1, mw1[j], fmaf(pn0, mw0[j], mbv[j])));
        FragU x0f; split4(x0, x0f.u);

        // ---- mlp: X^T = mlpw^T @ X0^T (exact via hi/lo), ELU ----
        f32x4 dx = {0.f,0.f,0.f,0.f};
        dx = __builtin_amdgcn_mfma_f32_16x16x32_bf16(mlpA[0].f, x0f.f, dx, 0,0,0);
        dx = __builtin_amdgcn_mfma_f32_16x16x32_bf16(mlpA[1].f, x0f.f, dx, 0,0,0);
        float xv[4];
        #pragma unroll
        for (int r = 0; r < 4; r++) xv[r] = elu_f(dx[r] + mlpbr[r]);
        // exact-X A-frag: k 0..3 (mod 8) = Xhi, k 4..7 (mod 8) = Xlo
        FragU xA; split4(xv, xA.u);

        float o0 = 0.f, o1 = 0.f;

        // ---- tiles 0..3: lift2 (MFMA) -> ELU -> hi-dup B-frag -> agg (1 MFMA) ----
        #pragma unroll
        for (int b = 0; b < 4; b++){
            f32x4 dl = {0.f,0.f,0.f,0.f};
            dl = __builtin_amdgcn_mfma_f32_16x16x32_bf16(hf[0].f, w2f[b][0].f, dl, 0,0,0);
            dl = __builtin_amdgcn_mfma_f32_16x16x32_bf16(hf[1].f, w2f[b][1].f, dl, 0,0,0);
            float fl[4];
            #pragma unroll
            for (int r = 0; r < 4; r++) fl[r] = elu_f(dl[r] + b2r[b]);
            FragU bfg;
            unsigned h01 = pk_bf16(fl[0], fl[1]), h23 = pk_bf16(fl[2], fl[3]);
            bfg.u[0] = h01; bfg.u[1] = h23; bfg.u[2] = h01; bfg.u[3] = h23;
            f32x4 da = {0.f,0.f,0.f,0.f};
            da = __builtin_amdgcn_mfma_f32_16x16x32_bf16(xA.f, bfg.f, da, 0,0,0);
            const float4 ew = *(const float4*)&sEndw[(b*16 + lo16)*20 + quad*4];
            float pt = da[0]*ew.x + da[1]*ew.y + da[2]*ew.z + da[3]*ew.w;
            pt += __shfl_xor(pt, 16, 64);
            pt += __shfl_xor(pt, 32, 64);
            if (b == quad) o0 = pt;            // c = b*16+lo16 == lane
        }
        // ---- tiles 4..7: raw F -> hi-dup B-frag -> agg (1 MFMA) ----
        #pragma unroll
        for (int bt = 0; bt < 4; bt++){
            FragU bfg;
            unsigned h01 = pk_bf16(fv[bt][0], fv[bt][1]);
            unsigned h23 = pk_bf16(fv[bt][2], fv[bt][3]);
            bfg.u[0] = h01; bfg.u[1] = h23; bfg.u[2] = h01; bfg.u[3] = h23;
            f32x4 da = {0.f,0.f,0.f,0.f};
            da = __builtin_amdgcn_mfma_f32_16x16x32_bf16(xA.f, bfg.f, da, 0,0,0);
            const float4 ew = *(const float4*)&sEndw[(64 + bt*16 + lo16)*20 + quad*4];
            float pt = da[0]*ew.x + da[1]*ew.y + da[2]*ew.z + da[3]*ew.w;
            pt += __shfl_xor(pt, 16, 64);
            pt += __shfl_xor(pt, 32, 64);
            if (bt == quad) o1 = pt;           // c = 64 + bt*16+lo16 == 64+lane
        }

        out[(size_t)nr*CM + lane]      = o0 + endb0;
        out[(size_t)nr*CM + 64 + lane] = o1 + endb1;
    }
}

extern "C" void kernel_launch(void* const* d_in, const int* in_sizes, int n_in,
                              void* d_out, int out_size, void* d_ws, size_t ws_size,
                              hipStream_t stream)
{
    const float* p     = (const float*)d_in[0];
    const float* P     = (const float*)d_in[1];
    const float* F     = (const float*)d_in[2];
    const float* gamma = (const float*)d_in[3];
    const float* beta  = (const float*)d_in[4];
    const float* w1    = (const float*)d_in[5];
    const float* b1    = (const float*)d_in[6];
    const float* w2    = (const float*)d_in[7];
    const float* b2    = (const float*)d_in[8];
    const float* midw  = (const float*)d_in[9];
    const float* midb  = (const float*)d_in[10];
    const float* mlpw  = (const float*)d_in[11];
    const float* mlpb  = (const float*)d_in[12];
    const float* endw  = (const float*)d_in[13];
    const float* endb  = (const float*)d_in[14];
    float* ws  = (float*)d_ws;
    float* out = (float*)d_out;

    hipMemsetAsync(d_ws, 0, 32, stream);
    xconv_stats<<<256, 256, 0, stream>>>(p, P, ws);
    xconv_main <<<1024, 256, 0, stream>>>(p, P, F, gamma, beta, w1, b1, w2, b2,
                                          midw, midb, mlpw, mlpb, endw, endb, ws, out);
}

// Round 5
// 148.287 us; speedup vs baseline: 1.5142x; 1.5142x over previous
//
#include <hip/hip_runtime.h>
#include <cstddef>

#define N_TOT   8
#define R_TOT   2048
#define NR_TOT  (N_TOT*R_TOT)      // 16384 points
#define KK      16
#define CL      64
#define CM      128
#define EPSV    1e-5f
#define CNTF    262144.0f

typedef float  f32x4  __attribute__((ext_vector_type(4)));
typedef short  bf16x8 __attribute__((ext_vector_type(8)));

union FragU { bf16x8 f; unsigned u[4]; };

__device__ __forceinline__ float elu_f(float x){
    return x > 0.f ? x : (__expf(x) - 1.f);
}

#if defined(__has_builtin) && __has_builtin(__builtin_amdgcn_cvt_pk_bf16_f32)
// gfx950 HW pack: 1 VALU op, RNE
__device__ __forceinline__ unsigned pk_bf16(float a, float b){
    auto v = __builtin_amdgcn_cvt_pk_bf16_f32(a, b);   // lo=a, hi=b
    unsigned u; __builtin_memcpy(&u, &v, 4);
    return u;
}
#else
__device__ __forceinline__ unsigned pk_bf16(float a, float b){   // RNE pack 2xbf16
    unsigned ua = __float_as_uint(a), ub = __float_as_uint(b);
    ua += 0x7fff + ((ua >> 16) & 1);
    ub += 0x7fff + ((ub >> 16) & 1);
    return (ua >> 16) | (ub & 0xffff0000u);
}
#endif
__device__ __forceinline__ float bf_lo(unsigned u){ return __uint_as_float(u << 16); }
__device__ __forceinline__ float bf_hi(unsigned u){ return __uint_as_float(u & 0xffff0000u); }

// split 4 floats -> (hi01, hi23, lo01, lo23); hi+lo == x to ~2^-17 rel
__device__ __forceinline__ void split4(const float* x, unsigned* o){
    unsigned h01 = pk_bf16(x[0], x[1]);
    unsigned h23 = pk_bf16(x[2], x[3]);
    float l0 = x[0] - bf_lo(h01), l1 = x[1] - bf_hi(h01);
    float l2 = x[2] - bf_lo(h23), l3 = x[3] - bf_hi(h23);
    o[0] = h01; o[1] = h23; o[2] = pk_bf16(l0, l1); o[3] = pk_bf16(l2, l3);
}

// ---------------- Pass 1: global BN stats (sum, sumsq per d) ----------------
__global__ __launch_bounds__(256) void xconv_stats(
    const float* __restrict__ p, const float* __restrict__ P, float* __restrict__ ws)
{
    float s1[3] = {0.f,0.f,0.f}, s2[3] = {0.f,0.f,0.f};
    const int total = NR_TOT * KK;
    for (int idx = blockIdx.x*256 + threadIdx.x; idx < total; idx += gridDim.x*256){
        int nr = idx >> 4;
        #pragma unroll
        for (int d = 0; d < 3; d++){
            float v = P[idx*3 + d] - p[nr*3 + d];
            s1[d] += v;
            s2[d] += v*v;
        }
    }
    #pragma unroll
    for (int off = 32; off > 0; off >>= 1){
        #pragma unroll
        for (int d = 0; d < 3; d++){
            s1[d] += __shfl_down(s1[d], off, 64);
            s2[d] += __shfl_down(s2[d], off, 64);
        }
    }
    __shared__ float red[4][6];
    int wave = threadIdx.x >> 6, lane = threadIdx.x & 63;
    if (lane == 0){
        #pragma unroll
        for (int d = 0; d < 3; d++){ red[wave][d] = s1[d]; red[wave][3+d] = s2[d]; }
    }
    __syncthreads();
    if (threadIdx.x < 6){
        float a = red[0][threadIdx.x] + red[1][threadIdx.x]
                + red[2][threadIdx.x] + red[3][threadIdx.x];
        atomicAdd(&ws[threadIdx.x], a);
    }
}

// ---------------- Pass 2: fused MFMA kernel ----------------
// 1024 blocks x 256 thr; each wave handles 4 points.
// NOTE: no min-waves launch bound — R4 showed __launch_bounds__(256,4) caps
// VGPR at 64 and spills ~50 regs of weight frags to scratch (FETCH 35->221MB).
__global__ __launch_bounds__(256) void xconv_main(
    const float* __restrict__ p,   const float* __restrict__ P,
    const float* __restrict__ F,
    const float* __restrict__ gamma,const float* __restrict__ beta,
    const float* __restrict__ w1,  const float* __restrict__ b1,
    const float* __restrict__ w2,  const float* __restrict__ b2,
    const float* __restrict__ midw,const float* __restrict__ midb,
    const float* __restrict__ mlpw,const float* __restrict__ mlpb,
    const float* __restrict__ endw,const float* __restrict__ endb,
    const float* __restrict__ ws,  float* __restrict__ out)
{
    __shared__ float sEndw[128*20];            // row stride 20 floats (80 B)

    const int tid  = threadIdx.x;
    const int lane = tid & 63;
    const int lo16 = lane & 15;
    const int quad = lane >> 4;
    const int wave = tid >> 6;

    // ---- stage endw [c][k] into LDS (rows padded to 80 B) ----
    {
        const float4* ep = (const float4*)endw;          // 512 float4
        float4 v0 = ep[tid*2], v1 = ep[tid*2 + 1];
        int c = tid >> 1, k0 = (tid & 1) * 8;
        float* dst = &sEndw[c*20 + k0];
        *(float4*)dst = v0; *(float4*)(dst + 4) = v1;
    }
    __syncthreads();

    // ---- BN scale/shift (finalize fused; uniform per wave) ----
    float sc[3], sh[3];
    #pragma unroll
    for (int d = 0; d < 3; d++){
        float mean = ws[d] / CNTF;
        float var  = ws[3+d] / CNTF - mean*mean;
        float s    = gamma[d] * rsqrtf(var + EPSV);
        sc[d] = s; sh[d] = beta[d] - mean*s;
    }

    // ---- static weight registers ----
    // w1/b1 packed bf16: q = s*32 + quad*8 + j
    unsigned w1pk[2][8][2];
    #pragma unroll
    for (int s = 0; s < 2; s++)
        #pragma unroll
        for (int j = 0; j < 8; j++){
            int q = s*32 + quad*8 + j;
            w1pk[s][j][0] = pk_bf16(w1[q],        w1[64 + q]);
            w1pk[s][j][1] = pk_bf16(w1[128 + q],  b1[q]);
        }
    // w2 B-frags: tile b (cols b*16+lo16), K-step s, rows quad*8+jj
    FragU w2f[4][2];
    #pragma unroll
    for (int b = 0; b < 4; b++)
        #pragma unroll
        for (int s = 0; s < 2; s++)
            #pragma unroll
            for (int d = 0; d < 4; d++){
                int q0 = s*32 + quad*8 + d*2;
                int idx = q0*64 + b*16 + lo16;
                w2f[b][s].u[d] = pk_bf16(w2[idx], w2[idx + 64]);
            }
    // mlp A-frags (mlpw^T, hi/lo split, quad-dup)
    FragU mlpA[2];
    {
        float mw[4];
        #pragma unroll
        for (int r = 0; r < 4; r++) mw[r] = mlpw[(quad*4 + r)*16 + lo16];
        unsigned o[4]; split4(mw, o);
        mlpA[0].u[0]=o[0]; mlpA[0].u[1]=o[1]; mlpA[0].u[2]=o[0]; mlpA[0].u[3]=o[1];
        mlpA[1].u[0]=o[2]; mlpA[1].u[1]=o[3]; mlpA[1].u[2]=o[2]; mlpA[1].u[3]=o[3];
    }
    float mlpbr[4];
    #pragma unroll
    for (int r = 0; r < 4; r++) mlpbr[r] = mlpb[quad*4 + r];
    // midw/midb for X0 cols quad*4+j
    float mw0[4], mw1[4], mw2[4], mbv[4];
    #pragma unroll
    for (int j = 0; j < 4; j++){
        int m2 = quad*4 + j;
        mw0[j] = midw[m2]; mw1[j] = midw[16 + m2]; mw2[j] = midw[32 + m2];
        mbv[j] = midb[m2];
    }
    float b2r[4];
    #pragma unroll
    for (int b = 0; b < 4; b++) b2r[b] = b2[b*16 + lo16];
    const float endb0 = endb[lane], endb1 = endb[64 + lane];

    const int wglobal = blockIdx.x*4 + wave;   // 0..4095

    #pragma unroll 1
    for (int it = 0; it < 4; it++){
        const int nr = wglobal*4 + it;

        // ---- issue all global loads up front (latency hidden by h1 VALU) ----
        const int pb = nr*48 + lo16*3;
        float P0 = P[pb], P1 = P[pb+1], P2 = P[pb+2];
        float pp0 = p[nr*3], pp1 = p[nr*3+1], pp2 = p[nr*3+2];
        float fv[4][4];                        // F[nr][quad*4+r][bt*16+lo16]
        #pragma unroll
        for (int bt = 0; bt < 4; bt++)
            #pragma unroll
            for (int r = 0; r < 4; r++)
                fv[bt][r] = F[(size_t)nr*1024 + (quad*4 + r)*64 + bt*16 + lo16];

        const float pn0 = (P0 - pp0)*sc[0] + sh[0];
        const float pn1 = (P1 - pp1)*sc[1] + sh[1];
        const float pn2 = (P2 - pp2)*sc[2] + sh[2];

        // ---- h1 A-frags (lift1 + ELU + bf16 pack), fully in-lane ----
        FragU hf[2];
        #pragma unroll
        for (int s = 0; s < 2; s++)
            #pragma unroll
            for (int d = 0; d < 4; d++){
                float e[2];
                #pragma unroll
                for (int h2 = 0; h2 < 2; h2++){
                    unsigned pa = w1pk[s][2*d + h2][0], pbk = w1pk[s][2*d + h2][1];
                    float h = bf_hi(pbk);
                    h = fmaf(pn0, bf_lo(pa), h);
                    h = fmaf(pn1, bf_hi(pa), h);
                    h = fmaf(pn2, bf_lo(pbk), h);
                    e[h2] = elu_f(h);
                }
                hf[s].u[d] = pk_bf16(e[0], e[1]);
            }

        // ---- X0 (exact fp32) -> split B-frag ----
        float x0[4];
        #pragma unroll
        for (int j = 0; j < 4; j++)
            x0[j] = fmaf(pn2, mw2[j], fmaf(pn1, mw1[j], fmaf(pn0, mw0[j], mbv[j])));
        FragU x0f; split4(x0, x0f.u);

        // ---- mlp: X^T = mlpw^T @ X0^T (exact via hi/lo), ELU ----
        f32x4 dx = {0.f,0.f,0.f,0.f};
        dx = __builtin_amdgcn_mfma_f32_16x16x32_bf16(mlpA[0].f, x0f.f, dx, 0,0,0);
        dx = __builtin_amdgcn_mfma_f32_16x16x32_bf16(mlpA[1].f, x0f.f, dx, 0,0,0);
        float xv[4];
        #pragma unroll
        for (int r = 0; r < 4; r++) xv[r] = elu_f(dx[r] + mlpbr[r]);
        // exact-X A-frag: k 0..3 (mod 8) = Xhi, k 4..7 (mod 8) = Xlo
        FragU xA; split4(xv, xA.u);

        float o0 = 0.f, o1 = 0.f;

        // ---- tiles 0..3: lift2 (MFMA) -> ELU -> hi-dup B-frag -> agg (1 MFMA) ----
        #pragma unroll
        for (int b = 0; b < 4; b++){
            f32x4 dl = {0.f,0.f,0.f,0.f};
            dl = __builtin_amdgcn_mfma_f32_16x16x32_bf16(hf[0].f, w2f[b][0].f, dl, 0,0,0);
            dl = __builtin_amdgcn_mfma_f32_16x16x32_bf16(hf[1].f, w2f[b][1].f, dl, 0,0,0);
            float fl[4];
            #pragma unroll
            for (int r = 0; r < 4; r++) fl[r] = elu_f(dl[r] + b2r[b]);
            FragU bfg;
            unsigned h01 = pk_bf16(fl[0], fl[1]), h23 = pk_bf16(fl[2], fl[3]);
            bfg.u[0] = h01; bfg.u[1] = h23; bfg.u[2] = h01; bfg.u[3] = h23;
            f32x4 da = {0.f,0.f,0.f,0.f};
            da = __builtin_amdgcn_mfma_f32_16x16x32_bf16(xA.f, bfg.f, da, 0,0,0);
            const float4 ew = *(const float4*)&sEndw[(b*16 + lo16)*20 + quad*4];
            float pt = da[0]*ew.x + da[1]*ew.y + da[2]*ew.z + da[3]*ew.w;
            pt += __shfl_xor(pt, 16, 64);
            pt += __shfl_xor(pt, 32, 64);
            if (b == quad) o0 = pt;            // c = b*16+lo16 == lane
        }
        // ---- tiles 4..7: raw F -> hi-dup B-frag -> agg (1 MFMA) ----
        #pragma unroll
        for (int bt = 0; bt < 4; bt++){
            FragU bfg;
            unsigned h01 = pk_bf16(fv[bt][0], fv[bt][1]);
            unsigned h23 = pk_bf16(fv[bt][2], fv[bt][3]);
            bfg.u[0] = h01; bfg.u[1] = h23; bfg.u[2] = h01; bfg.u[3] = h23;
            f32x4 da = {0.f,0.f,0.f,0.f};
            da = __builtin_amdgcn_mfma_f32_16x16x32_bf16(xA.f, bfg.f, da, 0,0,0);
            const float4 ew = *(const float4*)&sEndw[(64 + bt*16 + lo16)*20 + quad*4];
            float pt = da[0]*ew.x + da[1]*ew.y + da[2]*ew.z + da[3]*ew.w;
            pt += __shfl_xor(pt, 16, 64);
            pt += __shfl_xor(pt, 32, 64);
            if (bt == quad) o1 = pt;           // c = 64 + bt*16+lo16 == 64+lane
        }

        out[(size_t)nr*CM + lane]      = o0 + endb0;
        out[(size_t)nr*CM + 64 + lane] = o1 + endb1;
    }
}

extern "C" void kernel_launch(void* const* d_in, const int* in_sizes, int n_in,
                              void* d_out, int out_size, void* d_ws, size_t ws_size,
                              hipStream_t stream)
{
    const float* p     = (const float*)d_in[0];
    const float* P     = (const float*)d_in[1];
    const float* F     = (const float*)d_in[2];
    const float* gamma = (const float*)d_in[3];
    const float* beta  = (const float*)d_in[4];
    const float* w1    = (const float*)d_in[5];
    const float* b1    = (const float*)d_in[6];
    const float* w2    = (const float*)d_in[7];
    const float* b2    = (const float*)d_in[8];
    const float* midw  = (const float*)d_in[9];
    const float* midb  = (const float*)d_in[10];
    const float* mlpw  = (const float*)d_in[11];
    const float* mlpb  = (const float*)d_in[12];
    const float* endw  = (const float*)d_in[13];
    const float* endb  = (const float*)d_in[14];
    float* ws  = (float*)d_ws;
    float* out = (float*)d_out;

    hipMemsetAsync(d_ws, 0, 32, stream);
    xconv_stats<<<256, 256, 0, stream>>>(p, P, ws);
    xconv_main <<<1024, 256, 0, stream>>>(p, P, F, gamma, beta, w1, b1, w2, b2,
                                          midw, midb, mlpw, mlpb, endw, endb, ws, out);
}

// Round 6
// 147.731 us; speedup vs baseline: 1.5199x; 1.0038x over previous
//
#include <hip/hip_runtime.h>
#include <cstddef>

#define N_TOT   8
#define R_TOT   2048
#define NR_TOT  (N_TOT*R_TOT)      // 16384 points
#define KK      16
#define CL      64
#define CM      128
#define EPSV    1e-5f
#define CNTF    262144.0f

typedef float  f32x4  __attribute__((ext_vector_type(4)));
typedef short  bf16x8 __attribute__((ext_vector_type(8)));

union FragU { bf16x8 f; unsigned u[4]; };

__device__ __forceinline__ float elu_f(float x){
    return x > 0.f ? x : (__expf(x) - 1.f);
}

#if defined(__has_builtin) && __has_builtin(__builtin_amdgcn_cvt_pk_bf16_f32)
// gfx950 HW pack: 1 VALU op, RNE
__device__ __forceinline__ unsigned pk_bf16(float a, float b){
    auto v = __builtin_amdgcn_cvt_pk_bf16_f32(a, b);   // lo=a, hi=b
    unsigned u; __builtin_memcpy(&u, &v, 4);
    return u;
}
#else
__device__ __forceinline__ unsigned pk_bf16(float a, float b){   // RNE pack 2xbf16
    unsigned ua = __float_as_uint(a), ub = __float_as_uint(b);
    ua += 0x7fff + ((ua >> 16) & 1);
    ub += 0x7fff + ((ub >> 16) & 1);
    return (ua >> 16) | (ub & 0xffff0000u);
}
#endif
__device__ __forceinline__ float bf_lo(unsigned u){ return __uint_as_float(u << 16); }
__device__ __forceinline__ float bf_hi(unsigned u){ return __uint_as_float(u & 0xffff0000u); }

// split 4 floats -> (hi01, hi23, lo01, lo23); hi+lo == x to ~2^-17 rel
__device__ __forceinline__ void split4(const float* x, unsigned* o){
    unsigned h01 = pk_bf16(x[0], x[1]);
    unsigned h23 = pk_bf16(x[2], x[3]);
    float l0 = x[0] - bf_lo(h01), l1 = x[1] - bf_hi(h01);
    float l2 = x[2] - bf_lo(h23), l3 = x[3] - bf_hi(h23);
    o[0] = h01; o[1] = h23; o[2] = pk_bf16(l0, l1); o[3] = pk_bf16(l2, l3);
}

// ---------------- Pass 1: global BN stats (sum, sumsq per d) ----------------
// 256 blocks x 256 thr = 65536 threads; each handles 4 consecutive neighbor
// rows via 3 float4 loads (48 B/thread, fully coalesced, no loop).
__global__ __launch_bounds__(256) void xconv_stats(
    const float* __restrict__ p, const float* __restrict__ P, float* __restrict__ ws)
{
    const int g = blockIdx.x*256 + threadIdx.x;        // 0..65535 group of 4 idx
    const float4* P4 = (const float4*)(P + (size_t)g*12);
    float4 a = P4[0], b = P4[1], c = P4[2];
    const int nr = g >> 2;                             // 4 idx stay in one nr (16%4==0)
    float pp0 = p[nr*3], pp1 = p[nr*3+1], pp2 = p[nr*3+2];
    // layout: a={x0,y0,z0,x1} b={y1,z1,x2,y2} c={z2,x3,y3,z3}
    float vx0=a.x-pp0, vx1=a.w-pp0, vx2=b.z-pp0, vx3=c.y-pp0;
    float vy0=a.y-pp1, vy1=b.x-pp1, vy2=b.w-pp1, vy3=c.z-pp1;
    float vz0=a.z-pp2, vz1=b.y-pp2, vz2=c.x-pp2, vz3=c.w-pp2;
    float s1[3], s2[3];
    s1[0]=vx0+vx1+vx2+vx3; s2[0]=vx0*vx0+vx1*vx1+vx2*vx2+vx3*vx3;
    s1[1]=vy0+vy1+vy2+vy3; s2[1]=vy0*vy0+vy1*vy1+vy2*vy2+vy3*vy3;
    s1[2]=vz0+vz1+vz2+vz3; s2[2]=vz0*vz0+vz1*vz1+vz2*vz2+vz3*vz3;

    #pragma unroll
    for (int off = 32; off > 0; off >>= 1){
        #pragma unroll
        for (int d = 0; d < 3; d++){
            s1[d] += __shfl_down(s1[d], off, 64);
            s2[d] += __shfl_down(s2[d], off, 64);
        }
    }
    __shared__ float red[4][6];
    int wave = threadIdx.x >> 6, lane = threadIdx.x & 63;
    if (lane == 0){
        #pragma unroll
        for (int d = 0; d < 3; d++){ red[wave][d] = s1[d]; red[wave][3+d] = s2[d]; }
    }
    __syncthreads();
    if (threadIdx.x < 6){
        float v = red[0][threadIdx.x] + red[1][threadIdx.x]
                + red[2][threadIdx.x] + red[3][threadIdx.x];
        atomicAdd(&ws[threadIdx.x], v);
    }
}

// ---------------- Pass 2: fused MFMA kernel ----------------
// 1024 blocks x 256 thr; each wave handles 4 points.
// NOTE: no min-waves launch bound — R4 showed __launch_bounds__(256,4) caps
// VGPR at 64 and spills ~50 regs of weight frags to scratch (FETCH 35->221MB).
__global__ __launch_bounds__(256) void xconv_main(
    const float* __restrict__ p,   const float* __restrict__ P,
    const float* __restrict__ F,
    const float* __restrict__ gamma,const float* __restrict__ beta,
    const float* __restrict__ w1,  const float* __restrict__ b1,
    const float* __restrict__ w2,  const float* __restrict__ b2,
    const float* __restrict__ midw,const float* __restrict__ midb,
    const float* __restrict__ mlpw,const float* __restrict__ mlpb,
    const float* __restrict__ endw,const float* __restrict__ endb,
    const float* __restrict__ ws,  float* __restrict__ out)
{
    __shared__ float sEndw[128*20];            // row stride 20 floats (80 B)

    const int tid  = threadIdx.x;
    const int lane = tid & 63;
    const int lo16 = lane & 15;
    const int quad = lane >> 4;
    const int wave = tid >> 6;

    // ---- stage endw [c][k] into LDS (rows padded to 80 B) ----
    {
        const float4* ep = (const float4*)endw;          // 512 float4
        float4 v0 = ep[tid*2], v1 = ep[tid*2 + 1];
        int c = tid >> 1, k0 = (tid & 1) * 8;
        float* dst = &sEndw[c*20 + k0];
        *(float4*)dst = v0; *(float4*)(dst + 4) = v1;
    }
    __syncthreads();

    // ---- BN scale/shift (finalize fused; uniform per wave) ----
    float sc[3], sh[3];
    #pragma unroll
    for (int d = 0; d < 3; d++){
        float mean = ws[d] / CNTF;
        float var  = ws[3+d] / CNTF - mean*mean;
        float s    = gamma[d] * rsqrtf(var + EPSV);
        sc[d] = s; sh[d] = beta[d] - mean*s;
    }

    // ---- static weight registers ----
    // w1/b1 packed bf16: q = s*32 + quad*8 + j
    unsigned w1pk[2][8][2];
    #pragma unroll
    for (int s = 0; s < 2; s++)
        #pragma unroll
        for (int j = 0; j < 8; j++){
            int q = s*32 + quad*8 + j;
            w1pk[s][j][0] = pk_bf16(w1[q],        w1[64 + q]);
            w1pk[s][j][1] = pk_bf16(w1[128 + q],  b1[q]);
        }
    // w2 B-frags: tile b (cols b*16+lo16), K-step s, rows quad*8+jj
    FragU w2f[4][2];
    #pragma unroll
    for (int b = 0; b < 4; b++)
        #pragma unroll
        for (int s = 0; s < 2; s++)
            #pragma unroll
            for (int d = 0; d < 4; d++){
                int q0 = s*32 + quad*8 + d*2;
                int idx = q0*64 + b*16 + lo16;
                w2f[b][s].u[d] = pk_bf16(w2[idx], w2[idx + 64]);
            }
    // mlp A-frags (mlpw^T, hi/lo split, quad-dup)
    FragU mlpA[2];
    {
        float mw[4];
        #pragma unroll
        for (int r = 0; r < 4; r++) mw[r] = mlpw[(quad*4 + r)*16 + lo16];
        unsigned o[4]; split4(mw, o);
        mlpA[0].u[0]=o[0]; mlpA[0].u[1]=o[1]; mlpA[0].u[2]=o[0]; mlpA[0].u[3]=o[1];
        mlpA[1].u[0]=o[2]; mlpA[1].u[1]=o[3]; mlpA[1].u[2]=o[2]; mlpA[1].u[3]=o[3];
    }
    float mlpbr[4];
    #pragma unroll
    for (int r = 0; r < 4; r++) mlpbr[r] = mlpb[quad*4 + r];
    // midw/midb for X0 cols quad*4+j
    float mw0[4], mw1[4], mw2[4], mbv[4];
    #pragma unroll
    for (int j = 0; j < 4; j++){
        int m2 = quad*4 + j;
        mw0[j] = midw[m2]; mw1[j] = midw[16 + m2]; mw2[j] = midw[32 + m2];
        mbv[j] = midb[m2];
    }
    float b2r[4];
    #pragma unroll
    for (int b = 0; b < 4; b++) b2r[b] = b2[b*16 + lo16];
    const float endb0 = endb[lane], endb1 = endb[64 + lane];

    const int wglobal = blockIdx.x*4 + wave;   // 0..4095

    // ---- prefetch P/p for the first point (consumed at iteration head) ----
    float nP0, nP1, nP2, npp0, npp1, npp2;
    {
        const int nr0 = wglobal*4;
        const int pb  = nr0*48 + lo16*3;
        nP0 = P[pb]; nP1 = P[pb+1]; nP2 = P[pb+2];
        npp0 = p[nr0*3]; npp1 = p[nr0*3+1]; npp2 = p[nr0*3+2];
    }

    #pragma unroll 1
    for (int it = 0; it < 4; it++){
        const int nr = wglobal*4 + it;

        const float P0 = nP0, P1 = nP1, P2 = nP2;
        const float pp0 = npp0, pp1 = npp1, pp2 = npp2;

        // ---- fv loads: issued now, consumed ~1000 cyc later (tiles 4..7) ----
        float fv[4][4];                        // F[nr][quad*4+r][bt*16+lo16]
        #pragma unroll
        for (int bt = 0; bt < 4; bt++)
            #pragma unroll
            for (int r = 0; r < 4; r++)
                fv[bt][r] = F[(size_t)nr*1024 + (quad*4 + r)*64 + bt*16 + lo16];

        // ---- prefetch next iteration's P/p (hidden behind this point's chain) ----
        if (it < 3){
            const int nn = nr + 1;
            const int pb = nn*48 + lo16*3;
            nP0 = P[pb]; nP1 = P[pb+1]; nP2 = P[pb+2];
            npp0 = p[nn*3]; npp1 = p[nn*3+1]; npp2 = p[nn*3+2];
        }

        const float pn0 = (P0 - pp0)*sc[0] + sh[0];
        const float pn1 = (P1 - pp1)*sc[1] + sh[1];
        const float pn2 = (P2 - pp2)*sc[2] + sh[2];

        // ---- h1 A-frags (lift1 + ELU + bf16 pack), fully in-lane ----
        FragU hf[2];
        #pragma unroll
        for (int s = 0; s < 2; s++)
            #pragma unroll
            for (int d = 0; d < 4; d++){
                float e[2];
                #pragma unroll
                for (int h2 = 0; h2 < 2; h2++){
                    unsigned pa = w1pk[s][2*d + h2][0], pbk = w1pk[s][2*d + h2][1];
                    float h = bf_hi(pbk);
                    h = fmaf(pn0, bf_lo(pa), h);
                    h = fmaf(pn1, bf_hi(pa), h);
                    h = fmaf(pn2, bf_lo(pbk), h);
                    e[h2] = elu_f(h);
                }
                hf[s].u[d] = pk_bf16(e[0], e[1]);
            }

        // ---- X0 (exact fp32) -> split B-frag ----
        float x0[4];
        #pragma unroll
        for (int j = 0; j < 4; j++)
            x0[j] = fmaf(pn2, mw2[j], fmaf(pn1, mw1[j], fmaf(pn0, mw0[j], mbv[j])));
        FragU x0f; split4(x0, x0f.u);

        // ---- mlp: X^T = mlpw^T @ X0^T (exact via hi/lo), ELU ----
        f32x4 dx = {0.f,0.f,0.f,0.f};
        dx = __builtin_amdgcn_mfma_f32_16x16x32_bf16(mlpA[0].f, x0f.f, dx, 0,0,0);
        dx = __builtin_amdgcn_mfma_f32_16x16x32_bf16(mlpA[1].f, x0f.f, dx, 0,0,0);
        float xv[4];
        #pragma unroll
        for (int r = 0; r < 4; r++) xv[r] = elu_f(dx[r] + mlpbr[r]);
        // exact-X A-frag: k 0..3 (mod 8) = Xhi, k 4..7 (mod 8) = Xlo
        FragU xA; split4(xv, xA.u);

        float o0 = 0.f, o1 = 0.f;

        // ---- tiles 0..3: lift2 (MFMA) -> ELU -> hi-dup B-frag -> agg (1 MFMA) ----
        #pragma unroll
        for (int b = 0; b < 4; b++){
            f32x4 dl = {0.f,0.f,0.f,0.f};
            dl = __builtin_amdgcn_mfma_f32_16x16x32_bf16(hf[0].f, w2f[b][0].f, dl, 0,0,0);
            dl = __builtin_amdgcn_mfma_f32_16x16x32_bf16(hf[1].f, w2f[b][1].f, dl, 0,0,0);
            float fl[4];
            #pragma unroll
            for (int r = 0; r < 4; r++) fl[r] = elu_f(dl[r] + b2r[b]);
            FragU bfg;
            unsigned h01 = pk_bf16(fl[0], fl[1]), h23 = pk_bf16(fl[2], fl[3]);
            bfg.u[0] = h01; bfg.u[1] = h23; bfg.u[2] = h01; bfg.u[3] = h23;
            f32x4 da = {0.f,0.f,0.f,0.f};
            da = __builtin_amdgcn_mfma_f32_16x16x32_bf16(xA.f, bfg.f, da, 0,0,0);
            const float4 ew = *(const float4*)&sEndw[(b*16 + lo16)*20 + quad*4];
            float pt = da[0]*ew.x + da[1]*ew.y + da[2]*ew.z + da[3]*ew.w;
            pt += __shfl_xor(pt, 16, 64);
            pt += __shfl_xor(pt, 32, 64);
            if (b == quad) o0 = pt;            // c = b*16+lo16 == lane
        }
        // ---- tiles 4..7: raw F -> hi-dup B-frag -> agg (1 MFMA) ----
        #pragma unroll
        for (int bt = 0; bt < 4; bt++){
            FragU bfg;
            unsigned h01 = pk_bf16(fv[bt][0], fv[bt][1]);
            unsigned h23 = pk_bf16(fv[bt][2], fv[bt][3]);
            bfg.u[0] = h01; bfg.u[1] = h23; bfg.u[2] = h01; bfg.u[3] = h23;
            f32x4 da = {0.f,0.f,0.f,0.f};
            da = __builtin_amdgcn_mfma_f32_16x16x32_bf16(xA.f, bfg.f, da, 0,0,0);
            const float4 ew = *(const float4*)&sEndw[(64 + bt*16 + lo16)*20 + quad*4];
            float pt = da[0]*ew.x + da[1]*ew.y + da[2]*ew.z + da[3]*ew.w;
            pt += __shfl_xor(pt, 16, 64);
            pt += __shfl_xor(pt, 32, 64);
            if (bt == quad) o1 = pt;           // c = 64 + bt*16+lo16 == 64+lane
        }

        out[(size_t)nr*CM + lane]      = o0 + endb0;
        out[(size_t)nr*CM + 64 + lane] = o1 + endb1;
    }
}

extern "C" void kernel_launch(void* const* d_in, const int* in_sizes, int n_in,
                              void* d_out, int out_size, void* d_ws, size_t ws_size,
                              hipStream_t stream)
{
    const float* p     = (const float*)d_in[0];
    const float* P     = (const float*)d_in[1];
    const float* F     = (const float*)d_in[2];
    const float* gamma = (const float*)d_in[3];
    const float* beta  = (const float*)d_in[4];
    const float* w1    = (const float*)d_in[5];
    const float* b1    = (const float*)d_in[6];
    const float* w2    = (const float*)d_in[7];
    const float* b2    = (const float*)d_in[8];
    const float* midw  = (const float*)d_in[9];
    const float* midb  = (const float*)d_in[10];
    const float* mlpw  = (const float*)d_in[11];
    const float* mlpb  = (const float*)d_in[12];
    const float* endw  = (const float*)d_in[13];
    const float* endb  = (const float*)d_in[14];
    float* ws  = (float*)d_ws;
    float* out = (float*)d_out;

    hipMemsetAsync(d_ws, 0, 32, stream);
    xconv_stats<<<256, 256, 0, stream>>>(p, P, ws);
    xconv_main <<<1024, 256, 0, stream>>>(p, P, F, gamma, beta, w1, b1, w2, b2,
                                          midw, midb, mlpw, mlpb, endw, endb, ws, out);
}